// Round 9
// baseline (150.713 us; speedup 1.0000x reference)
//
#include <hip/hip_runtime.h>
#include <hip/hip_bf16.h>

typedef __bf16 bf16x8 __attribute__((ext_vector_type(8)));
typedef __bf16 bf16x4 __attribute__((ext_vector_type(4)));
typedef __bf16 bf16x2 __attribute__((ext_vector_type(2)));
typedef float  f32x4  __attribute__((ext_vector_type(4)));
typedef float  f32x16v __attribute__((ext_vector_type(16)));

#define MFMA16(A,B,Cc) __builtin_amdgcn_mfma_f32_16x16x32_bf16(A,B,Cc,0,0,0)
#define MFMA32(A,B,Cc) __builtin_amdgcn_mfma_f32_32x32x16_bf16(A,B,Cc,0,0,0)

__device__ inline unsigned pack2(float a, float b) {
  union { bf16x2 v; unsigned u; } t;
  t.v[0] = (__bf16)a; t.v[1] = (__bf16)b;
  return t.u;
}
__device__ inline bf16x8 frag4(unsigned w0, unsigned w1, unsigned w2, unsigned w3) {
  union { unsigned u[4]; bf16x8 v; } t;
  t.u[0] = w0; t.u[1] = w1; t.u[2] = w2; t.u[3] = w3;
  return t.v;
}

// lane-row swap: after call, a = {a.row0 | b.row0(from lane-32)},
//                            b = {a.row1(from lane+32) | b.row1}
__device__ inline void pswap(unsigned& a, unsigned& b) {
#if __has_builtin(__builtin_amdgcn_permlane32_swap)
  auto r = __builtin_amdgcn_permlane32_swap(a, b, false, false);
  a = r[0]; b = r[1];
#else
  asm volatile("v_permlane32_swap_b32 %0, %1" : "+v"(a), "+v"(b));
#endif
}
__device__ inline float cross32_max(float v) {
  unsigned a = __builtin_bit_cast(unsigned, v), b = a;
  pswap(a, b);
  return fmaxf(__builtin_bit_cast(float, a), __builtin_bit_cast(float, b));
}
__device__ inline float cross32_sum(float v) {
  unsigned a = __builtin_bit_cast(unsigned, v), b = a;
  pswap(a, b);
  return __builtin_bit_cast(float, a) + __builtin_bit_cast(float, b);
}

// ---------------- f32 -> bf16 pre-convert (x + 4 weight matrices) ----------------
__global__ __launch_bounds__(256) void conv_kernel(
    const float* __restrict__ x,
    const float* __restrict__ Wq, const float* __restrict__ Wk,
    const float* __restrict__ Wv, const float* __restrict__ Wp,
    __bf16* __restrict__ xb, __bf16* __restrict__ Wb)
{
  const int z = blockIdx.y;
  const float* src;
  __bf16* dst;
  int n4;
  if (z == 0) { src = x;  dst = xb; n4 = 1048576; }
  else {
    src = (z == 1) ? Wq : (z == 2) ? Wk : (z == 3) ? Wv : Wp;
    dst = Wb + (size_t)(z - 1) * 1048576;
    n4  = 262144;
  }
  const f32x4* s4 = (const f32x4*)src;
  for (int i = blockIdx.x * 256 + threadIdx.x; i < n4; i += gridDim.x * 256) {
    const f32x4 v = s4[i];
    bf16x4 o;
#pragma unroll
    for (int j = 0; j < 4; ++j) o[j] = (__bf16)v[j];
    *(bf16x4*)(dst + (size_t)i * 4) = o;
  }
}

// ---------------- shared 128x128x(K=1024) bf16 MFMA core ----------------
__device__ inline void gemm_core(const __bf16* __restrict__ A,
                                 const __bf16* __restrict__ W,
                                 int m0, int n0,
                                 __bf16* As, __bf16* Bs,
                                 f32x4 (&acc)[4][4])
{
  const int tid = threadIdx.x, lane = tid & 63;
  const int wid = tid >> 6, wr = wid >> 1, wc = wid & 1;
  const int g = lane >> 4, cl = lane & 15;
  const int sr = tid >> 2, sk = (tid & 3) * 8;

  for (int k0 = 0; k0 < 1024; k0 += 32) {
    bf16x8 a0 = *(const bf16x8*)(A + (size_t)(m0 + sr)      * 1024 + k0 + sk);
    bf16x8 a1 = *(const bf16x8*)(A + (size_t)(m0 + sr + 64) * 1024 + k0 + sk);
    bf16x8 b0 = *(const bf16x8*)(W + (size_t)(n0 + sr)      * 1024 + k0 + sk);
    bf16x8 b1 = *(const bf16x8*)(W + (size_t)(n0 + sr + 64) * 1024 + k0 + sk);
    __syncthreads();
    *(bf16x8*)(As + sr * 32 + sk)        = a0;
    *(bf16x8*)(As + (sr + 64) * 32 + sk) = a1;
    *(bf16x8*)(Bs + sr * 32 + sk)        = b0;
    *(bf16x8*)(Bs + (sr + 64) * 32 + sk) = b1;
    __syncthreads();
    bf16x8 af[4], bfr[4];
#pragma unroll
    for (int m = 0; m < 4; ++m)
      af[m] = *(const bf16x8*)(As + (wr * 64 + m * 16 + cl) * 32 + g * 8);
#pragma unroll
    for (int n = 0; n < 4; ++n)
      bfr[n] = *(const bf16x8*)(Bs + (wc * 64 + n * 16 + cl) * 32 + g * 8);
#pragma unroll
    for (int m = 0; m < 4; ++m)
#pragma unroll
      for (int n = 0; n < 4; ++n)
        acc[m][n] = MFMA16(af[m], bfr[n], acc[m][n]);
  }
}

// ---------------- fused QKV GEMM (bf16 in, scattered bf16 out) ----------------
__global__ __launch_bounds__(256) void gemm_qkv128(
    const __bf16* __restrict__ xb, const __bf16* __restrict__ Wb,
    const float* __restrict__ bq, const float* __restrict__ bk,
    const float* __restrict__ bv,
    __bf16* __restrict__ Qw, __bf16* __restrict__ Kw, __bf16* __restrict__ Vw)
{
  __shared__ __align__(16) __bf16 As[128 * 32];
  __shared__ __align__(16) __bf16 Bs[128 * 32];

  const int orig = blockIdx.x;
  const int wg   = (orig & 7) * 96 + (orig >> 3);   // bijective: 768 = 8*96
  const int z    = wg >> 8;
  const int rem  = wg & 255;
  const int m0   = (rem >> 3) * 128;
  const int n0   = (rem & 7) * 128;

  const __bf16* W  = Wb + (size_t)z * 1048576;
  const float*  bi = (z == 0) ? bq : (z == 1) ? bk : bv;
  __bf16*       out = (z == 0) ? Qw : (z == 1) ? Kw : Vw;

  f32x4 acc[4][4] = {};
  gemm_core(xb, W, m0, n0, As, Bs, acc);

  const int lane = threadIdx.x & 63, wid = threadIdx.x >> 6;
  const int wr = wid >> 1, wc = wid & 1;
  const int g = lane >> 4, cl = lane & 15;

  float bvv[4];
#pragma unroll
  for (int n = 0; n < 4; ++n) bvv[n] = bi[n0 + wc * 64 + n * 16 + cl];

#pragma unroll
  for (int m = 0; m < 4; ++m)
#pragma unroll
    for (int n = 0; n < 4; ++n) {
      const int col = n0 + wc * 64 + n * 16 + cl;
      const int h = col >> 6, d = col & 63;
      if (z == 2) {                               // V^T scatter [BH][D][T]
        const int row0 = m0 + wr * 64 + m * 16 + g * 4;
        const int b2 = row0 >> 11, t0 = row0 & 2047;
        bf16x4 v4;
#pragma unroll
        for (int j = 0; j < 4; ++j) v4[j] = (__bf16)(acc[m][n][j] + bvv[n]);
        *(bf16x4*)(out + (size_t)(b2 * 16 + h) * 131072 + (size_t)d * 2048 + t0) = v4;
      } else {                                    // Q/K scatter [BH][T][D]
#pragma unroll
        for (int j = 0; j < 4; ++j) {
          const int row = m0 + wr * 64 + m * 16 + g * 4 + j;
          const int b2 = row >> 11, t = row & 2047;
          out[(size_t)(b2 * 16 + h) * 131072 + (size_t)t * 64 + d] =
              (__bf16)(acc[m][n][j] + bvv[n]);
        }
      }
    }
}

// ---------------- projection GEMM (bf16 in, f32 out) ----------------
__global__ __launch_bounds__(256) void gemm_proj128(
    const __bf16* __restrict__ A, const __bf16* __restrict__ W,
    const float* __restrict__ bi, float* __restrict__ outp)
{
  __shared__ __align__(16) __bf16 As[128 * 32];
  __shared__ __align__(16) __bf16 Bs[128 * 32];

  const int orig = blockIdx.x;
  const int wg   = (orig & 7) * 32 + (orig >> 3);   // bijective: 256 = 8*32
  const int m0   = (wg >> 3) * 128;
  const int n0   = (wg & 7) * 128;

  f32x4 acc[4][4] = {};
  gemm_core(A, W, m0, n0, As, Bs, acc);

  const int lane = threadIdx.x & 63, wid = threadIdx.x >> 6;
  const int wr = wid >> 1, wc = wid & 1;
  const int g = lane >> 4, cl = lane & 15;

  float bvv[4];
#pragma unroll
  for (int n = 0; n < 4; ++n) bvv[n] = bi[n0 + wc * 64 + n * 16 + cl];
#pragma unroll
  for (int m = 0; m < 4; ++m)
#pragma unroll
    for (int n = 0; n < 4; ++n) {
      const int col = n0 + wc * 64 + n * 16 + cl;
#pragma unroll
      for (int j = 0; j < 4; ++j) {
        const int row = m0 + wr * 64 + m * 16 + g * 4 + j;
        outp[(size_t)row * 1024 + col] = acc[m][n][j] + bvv[n];
      }
    }
}

// ---------------- causal flash attention: strip-paired + permlane + K-prefetch ----
__global__ __launch_bounds__(256, 4) void attn_kernel(
    const __bf16* __restrict__ Q, const __bf16* __restrict__ K,
    const __bf16* __restrict__ Vt, __bf16* __restrict__ Oc)
{
  const int bh  = blockIdx.x;
  const int p   = blockIdx.y;                   // pair: strips p and 63-p
  const int w   = threadIdx.x >> 6;
  const int lane = threadIdx.x & 63;
  const int l31 = lane & 31, hi = lane >> 5;
  const float SC = 0.18033688f;                 // 0.125 * log2(e)
  const float DT = 16.6f;                       // defer-max: P bounded by 2^3

  const __bf16* Qb = Q  + (size_t)bh * 131072;
  const __bf16* Kb = K  + (size_t)bh * 131072;
  const __bf16* Vb = Vt + (size_t)bh * 131072;
  const __bf16* vrow0 = Vb + (size_t)l31 * 2048;
  const __bf16* vrow1 = Vb + (size_t)(32 + l31) * 2048;

  __shared__ __bf16 SO[8][64][34];              // partial O (bf16), pad->no conflicts
  __shared__ float  SML[8][64][2];              // partial M, L

  const int qsS[2] = { p * 32, (63 - p) * 32 };
  const int nS[2]  = { p + 1, 64 - p };

#pragma unroll
  for (int ph = 0; ph < 2; ++ph) {
    const int qs = qsS[ph], nT = nS[ph];
    bf16x8 qf[4];
#pragma unroll
    for (int c = 0; c < 4; ++c)
      qf[c] = *(const bf16x8*)(Qb + (qs + l31) * 64 + c * 16 + hi * 8);

    f32x16v o0 = {}, o1 = {};
    float M = -1e30f, L = 0.f;
    float MS = M * SC;

    bf16x8 kf[4];                               // prefetched K fragments
#pragma unroll
    for (int c = 0; c < 4; ++c)
      kf[c] = *(const bf16x8*)(Kb + (w * 32 + l31) * 64 + c * 16 + hi * 8);

    for (int t = w; t < nT; t += 4) {
      const int kv0 = t * 32;
      const int tn = t + 4;
      bf16x8 kn[4];
      const bool hasNext = tn < nT;
      if (hasNext) {
#pragma unroll
        for (int c = 0; c < 4; ++c)
          kn[c] = *(const bf16x8*)(Kb + (tn * 32 + l31) * 64 + c * 16 + hi * 8);
      }

      // QK^T: two independent accumulate chains, then add
      f32x16v sA = {}, sB = {};
      sA = MFMA32(kf[0], qf[0], sA);
      sB = MFMA32(kf[1], qf[1], sB);
      sA = MFMA32(kf[2], qf[2], sA);
      sB = MFMA32(kf[3], qf[3], sB);
      f32x16v s = sA + sB;

      if (t == nT - 1) {                        // diagonal tile: mask k > q
#pragma unroll
        for (int r = 0; r < 16; ++r) {
          const int kl = (r & 3) + 8 * (r >> 2) + 4 * hi;
          if (kl > l31) s[r] = -1e30f;
        }
      }
      float mt = fmaxf(s[0], s[1]);
#pragma unroll
      for (int r = 2; r < 16; ++r) mt = fmaxf(mt, s[r]);
      mt = cross32_max(mt);
      if (!__all(mt <= M + DT)) {
        const float Mn = fmaxf(M, mt);
        const float rs = exp2f((M - Mn) * SC);
        o0 *= rs; o1 *= rs; L *= rs; M = Mn; MS = M * SC;
      }
      float pr[16];
      float lt = 0.f;
#pragma unroll
      for (int r = 0; r < 16; ++r) {
        pr[r] = exp2f(__builtin_fmaf(s[r], SC, -MS));
        lt += pr[r];
      }
      L += cross32_sum(lt);

      // P-pack: 8 cvt_pk + 4 permlane32_swap (no LDS cross-lane ops)
      unsigned c0 = pack2(pr[0],  pr[1]),  c1 = pack2(pr[2],  pr[3]);
      unsigned c2 = pack2(pr[4],  pr[5]),  c3 = pack2(pr[6],  pr[7]);
      unsigned c4 = pack2(pr[8],  pr[9]),  c5 = pack2(pr[10], pr[11]);
      unsigned c6 = pack2(pr[12], pr[13]), c7 = pack2(pr[14], pr[15]);
      pswap(c0, c2);   // c0 -> pf0 word0, c2 -> pf0 word2
      pswap(c1, c3);   // c1 -> pf0 word1, c3 -> pf0 word3
      pswap(c4, c6);
      pswap(c5, c7);
      const bf16x8 pf0 = frag4(c0, c1, c2, c3);
      const bf16x8 pf1 = frag4(c4, c5, c6, c7);

      bf16x8 va;
      va = *(const bf16x8*)(vrow0 + kv0 + hi * 8);       o0 = MFMA32(va, pf0, o0);
      va = *(const bf16x8*)(vrow1 + kv0 + hi * 8);       o1 = MFMA32(va, pf0, o1);
      va = *(const bf16x8*)(vrow0 + kv0 + 16 + hi * 8);  o0 = MFMA32(va, pf1, o0);
      va = *(const bf16x8*)(vrow1 + kv0 + 16 + hi * 8);  o1 = MFMA32(va, pf1, o1);

      if (hasNext) {
#pragma unroll
        for (int c = 0; c < 4; ++c) kf[c] = kn[c];
      }
    }

    const int slot = ph * 4 + w;
#pragma unroll
    for (int q4 = 0; q4 < 4; ++q4) {
      bf16x4 a, b;
#pragma unroll
      for (int j = 0; j < 4; ++j) {
        a[j] = (__bf16)o0[q4 * 4 + j];
        b[j] = (__bf16)o1[q4 * 4 + j];
      }
      *(bf16x4*)&SO[slot][lane][q4 * 4]      = a;
      *(bf16x4*)&SO[slot][lane][16 + q4 * 4] = b;
    }
    SML[slot][lane][0] = M;
    SML[slot][lane][1] = L;
  }

  __syncthreads();
  if (w < 2) {                                  // wave 0 -> strip A, wave 1 -> strip B
    const int base = w * 4;
    const int qs = qsS[w];
    float Mw[4], Lw[4];
#pragma unroll
    for (int s = 0; s < 4; ++s) {
      Mw[s] = SML[base + s][lane][0];
      Lw[s] = SML[base + s][lane][1];
    }
    const float Ms = fmaxf(fmaxf(Mw[0], Mw[1]), fmaxf(Mw[2], Mw[3]));
    float r[4], Lt = 0.f;
#pragma unroll
    for (int s = 0; s < 4; ++s) {
      r[s] = exp2f((Mw[s] - Ms) * SC);
      Lt += Lw[s] * r[s];
    }
    const float inv = 1.0f / Lt;

    const int b = bh >> 4, h = bh & 15;
    const int tq = qs + l31;
    __bf16* orow = Oc + (size_t)(b * 2048 + tq) * 1024 + h * 64;
#pragma unroll
    for (int q4 = 0; q4 < 4; ++q4) {
      bf16x4 v0, v1;
      float acc0[4] = {}, acc1[4] = {};
#pragma unroll
      for (int s = 0; s < 4; ++s) {
        const bf16x4 a4 = *(const bf16x4*)&SO[base + s][lane][q4 * 4];
        const bf16x4 b4 = *(const bf16x4*)&SO[base + s][lane][16 + q4 * 4];
#pragma unroll
        for (int j = 0; j < 4; ++j) {
          acc0[j] += (float)a4[j] * r[s];
          acc1[j] += (float)b4[j] * r[s];
        }
      }
#pragma unroll
      for (int j = 0; j < 4; ++j) {
        v0[j] = (__bf16)(acc0[j] * inv);
        v1[j] = (__bf16)(acc1[j] * inv);
      }
      const int d0 = 8 * q4 + 4 * hi;
      *(bf16x4*)(orow + d0)      = v0;
      *(bf16x4*)(orow + 32 + d0) = v1;
    }
  }
}

extern "C" void kernel_launch(void* const* d_in, const int* in_sizes, int n_in,
                              void* d_out, int out_size, void* d_ws, size_t ws_size,
                              hipStream_t stream) {
  const float* x  = (const float*)d_in[0];
  const float* Wq = (const float*)d_in[1];
  const float* bq = (const float*)d_in[2];
  const float* Wk = (const float*)d_in[3];
  const float* bk = (const float*)d_in[4];
  const float* Wv = (const float*)d_in[5];
  const float* bv = (const float*)d_in[6];
  const float* Wp = (const float*)d_in[7];
  const float* bp = (const float*)d_in[8];

  __bf16* Qw  = (__bf16*)d_ws;                 // [32][2048][64]  8 MB
  __bf16* Kw  = Qw + (size_t)4194304;          // [32][2048][64]  8 MB
  __bf16* Vw  = Kw + (size_t)4194304;          // [32][64][2048]  8 MB (V^T)
  __bf16* xbA = Vw + (size_t)4194304;          // 8 MB: xb, then reused as Aw
  __bf16* Wb  = xbA + (size_t)4194304;         // [4][1024][1024] 8 MB bf16 weights

  conv_kernel<<<dim3(512, 5), 256, 0, stream>>>(x, Wq, Wk, Wv, Wp, xbA, Wb);
  gemm_qkv128<<<768, 256, 0, stream>>>(xbA, Wb, bq, bk, bv, Qw, Kw, Vw);
  attn_kernel<<<dim3(32, 32), 256, 0, stream>>>(Qw, Kw, Vw, xbA /*Aw*/);
  gemm_proj128<<<256, 256, 0, stream>>>(xbA /*Aw*/, Wb + (size_t)3 * 1048576,
                                        bp, (float*)d_out);
}

// Round 10
// 137.759 us; speedup vs baseline: 1.0940x; 1.0940x over previous
//
#include <hip/hip_runtime.h>
#include <hip/hip_bf16.h>
#include <stdint.h>

typedef __bf16 bf16x8 __attribute__((ext_vector_type(8)));
typedef __bf16 bf16x4 __attribute__((ext_vector_type(4)));
typedef __bf16 bf16x2 __attribute__((ext_vector_type(2)));
typedef float  f32x4  __attribute__((ext_vector_type(4)));
typedef float  f32x16v __attribute__((ext_vector_type(16)));

#define MFMA16(A,B,Cc) __builtin_amdgcn_mfma_f32_16x16x32_bf16(A,B,Cc,0,0,0)
#define MFMA32(A,B,Cc) __builtin_amdgcn_mfma_f32_32x32x16_bf16(A,B,Cc,0,0,0)

__device__ inline unsigned pack2(float a, float b) {
  union { bf16x2 v; unsigned u; } t;
  t.v[0] = (__bf16)a; t.v[1] = (__bf16)b;
  return t.u;
}
__device__ inline bf16x8 frag4(unsigned w0, unsigned w1, unsigned w2, unsigned w3) {
  union { unsigned u[4]; bf16x8 v; } t;
  t.u[0] = w0; t.u[1] = w1; t.u[2] = w2; t.u[3] = w3;
  return t.v;
}

// async global->LDS, 16 B per lane; dest is wave-uniform base + lane*16
__device__ inline void gl16(const __bf16* g, __bf16* l) {
  __builtin_amdgcn_global_load_lds(
      (const __attribute__((address_space(1))) void*)(uintptr_t)g,
      (__attribute__((address_space(3))) void*)(uintptr_t)l, 16, 0, 0);
}

// ---------------- f32 -> bf16 pre-convert (x + 4 weight matrices) ----------------
__global__ __launch_bounds__(256) void conv_kernel(
    const float* __restrict__ x,
    const float* __restrict__ Wq, const float* __restrict__ Wk,
    const float* __restrict__ Wv, const float* __restrict__ Wp,
    __bf16* __restrict__ xb, __bf16* __restrict__ Wb)
{
  const int z = blockIdx.y;
  const float* src;
  __bf16* dst;
  int n4;
  if (z == 0) { src = x;  dst = xb; n4 = 1048576; }
  else {
    src = (z == 1) ? Wq : (z == 2) ? Wk : (z == 3) ? Wv : Wp;
    dst = Wb + (size_t)(z - 1) * 1048576;
    n4  = 262144;
  }
  const f32x4* s4 = (const f32x4*)src;
  for (int i = blockIdx.x * 256 + threadIdx.x; i < n4; i += gridDim.x * 256) {
    const f32x4 v = s4[i];
    bf16x4 o;
#pragma unroll
    for (int j = 0; j < 4; ++j) o[j] = (__bf16)v[j];
    *(bf16x4*)(dst + (size_t)i * 4) = o;
  }
}

// ---------------- shared 128x128x(K=1024) bf16 MFMA core (gload_lds staging) ----
__device__ inline void gemm_core(const __bf16* __restrict__ A,
                                 const __bf16* __restrict__ W,
                                 int m0, int n0,
                                 __bf16* As, __bf16* Bs,
                                 f32x4 (&acc)[4][4])
{
  const int tid = threadIdx.x, lane = tid & 63;
  const int wid = tid >> 6, wr = wid >> 1, wc = wid & 1;
  const int g = lane >> 4, cl = lane & 15;
  const int sr = tid >> 2, sk = (tid & 3) * 8;
  __bf16* AsW = As + (tid & 192) * 8;   // wave-uniform dest; lane*16B implied
  __bf16* BsW = Bs + (tid & 192) * 8;

  for (int k0 = 0; k0 < 1024; k0 += 32) {
    __syncthreads();                    // prev iter's LDS reads done
    gl16(A + (size_t)(m0 + sr)      * 1024 + k0 + sk, AsW);
    gl16(A + (size_t)(m0 + sr + 64) * 1024 + k0 + sk, AsW + 2048);
    gl16(W + (size_t)(n0 + sr)      * 1024 + k0 + sk, BsW);
    gl16(W + (size_t)(n0 + sr + 64) * 1024 + k0 + sk, BsW + 2048);
    __syncthreads();                    // vmcnt(0) drained before barrier
    bf16x8 af[4], bfr[4];
#pragma unroll
    for (int m = 0; m < 4; ++m)
      af[m] = *(const bf16x8*)(As + (wr * 64 + m * 16 + cl) * 32 + g * 8);
#pragma unroll
    for (int n = 0; n < 4; ++n)
      bfr[n] = *(const bf16x8*)(Bs + (wc * 64 + n * 16 + cl) * 32 + g * 8);
#pragma unroll
    for (int m = 0; m < 4; ++m)
#pragma unroll
      for (int n = 0; n < 4; ++n)
        acc[m][n] = MFMA16(af[m], bfr[n], acc[m][n]);
  }
}

// ---------------- fused QKV GEMM (bf16 in, scattered bf16 out) ----------------
__global__ __launch_bounds__(256) void gemm_qkv128(
    const __bf16* __restrict__ xb, const __bf16* __restrict__ Wb,
    const float* __restrict__ bq, const float* __restrict__ bk,
    const float* __restrict__ bv,
    __bf16* __restrict__ Qw, __bf16* __restrict__ Kw, __bf16* __restrict__ Vw)
{
  __shared__ __align__(16) __bf16 As[128 * 32];
  __shared__ __align__(16) __bf16 Bs[128 * 32];

  const int orig = blockIdx.x;
  const int wg   = (orig & 7) * 96 + (orig >> 3);   // bijective: 768 = 8*96
  const int z    = wg >> 8;
  const int rem  = wg & 255;
  const int m0   = (rem >> 3) * 128;
  const int n0   = (rem & 7) * 128;

  const __bf16* W  = Wb + (size_t)z * 1048576;
  const float*  bi = (z == 0) ? bq : (z == 1) ? bk : bv;
  __bf16*       out = (z == 0) ? Qw : (z == 1) ? Kw : Vw;

  f32x4 acc[4][4] = {};
  gemm_core(xb, W, m0, n0, As, Bs, acc);

  const int lane = threadIdx.x & 63, wid = threadIdx.x >> 6;
  const int wr = wid >> 1, wc = wid & 1;
  const int g = lane >> 4, cl = lane & 15;

  float bvv[4];
#pragma unroll
  for (int n = 0; n < 4; ++n) bvv[n] = bi[n0 + wc * 64 + n * 16 + cl];

#pragma unroll
  for (int m = 0; m < 4; ++m)
#pragma unroll
    for (int n = 0; n < 4; ++n) {
      const int col = n0 + wc * 64 + n * 16 + cl;
      const int h = col >> 6, d = col & 63;
      if (z == 2) {                               // V^T scatter [BH][D][T]
        const int row0 = m0 + wr * 64 + m * 16 + g * 4;
        const int b2 = row0 >> 11, t0 = row0 & 2047;
        bf16x4 v4;
#pragma unroll
        for (int j = 0; j < 4; ++j) v4[j] = (__bf16)(acc[m][n][j] + bvv[n]);
        *(bf16x4*)(out + (size_t)(b2 * 16 + h) * 131072 + (size_t)d * 2048 + t0) = v4;
      } else {                                    // Q/K scatter [BH][T][D]
#pragma unroll
        for (int j = 0; j < 4; ++j) {
          const int row = m0 + wr * 64 + m * 16 + g * 4 + j;
          const int b2 = row >> 11, t = row & 2047;
          out[(size_t)(b2 * 16 + h) * 131072 + (size_t)t * 64 + d] =
              (__bf16)(acc[m][n][j] + bvv[n]);
        }
      }
    }
}

// ---------------- projection GEMM (bf16 in, f32 out) ----------------
__global__ __launch_bounds__(256) void gemm_proj128(
    const __bf16* __restrict__ A, const __bf16* __restrict__ W,
    const float* __restrict__ bi, float* __restrict__ outp)
{
  __shared__ __align__(16) __bf16 As[128 * 32];
  __shared__ __align__(16) __bf16 Bs[128 * 32];

  const int orig = blockIdx.x;
  const int wg   = (orig & 7) * 32 + (orig >> 3);   // bijective: 256 = 8*32
  const int m0   = (wg >> 3) * 128;
  const int n0   = (wg & 7) * 128;

  f32x4 acc[4][4] = {};
  gemm_core(A, W, m0, n0, As, Bs, acc);

  const int lane = threadIdx.x & 63, wid = threadIdx.x >> 6;
  const int wr = wid >> 1, wc = wid & 1;
  const int g = lane >> 4, cl = lane & 15;

  float bvv[4];
#pragma unroll
  for (int n = 0; n < 4; ++n) bvv[n] = bi[n0 + wc * 64 + n * 16 + cl];
#pragma unroll
  for (int m = 0; m < 4; ++m)
#pragma unroll
    for (int n = 0; n < 4; ++n) {
      const int col = n0 + wc * 64 + n * 16 + cl;
#pragma unroll
      for (int j = 0; j < 4; ++j) {
        const int row = m0 + wr * 64 + m * 16 + g * 4 + j;
        outp[(size_t)row * 1024 + col] = acc[m][n][j] + bvv[n];
      }
    }
}

// ---------------- causal flash attention: strip-paired (r8 body + pad fix) ----------
__device__ inline void attn_tile(
    const __bf16* __restrict__ Kb, const __bf16* __restrict__ vrow0,
    const __bf16* __restrict__ vrow1, const bf16x8 (&qf)[4],
    int kv0, bool diag, int l31, int hi,
    float& M, float& MS, float& L, f32x16v& o0, f32x16v& o1)
{
  const float SC = 0.18033688f;                 // 0.125 * log2(e)
  const float DT = 16.6f;                       // defer-max: P bounded by 2^3
  f32x16v s = {};
#pragma unroll
  for (int c = 0; c < 4; ++c) {
    bf16x8 kf = *(const bf16x8*)(Kb + (kv0 + l31) * 64 + c * 16 + hi * 8);
    s = MFMA32(kf, qf[c], s);
  }
  float sv[16];
#pragma unroll
  for (int r = 0; r < 16; ++r) sv[r] = s[r];
  if (diag) {
#pragma unroll
    for (int r = 0; r < 16; ++r) {
      const int kl = (r & 3) + 8 * (r >> 2) + 4 * hi;
      if (kl > l31) sv[r] = -1e30f;
    }
  }
  float mt = sv[0];
#pragma unroll
  for (int r = 1; r < 16; ++r) mt = fmaxf(mt, sv[r]);
  mt = fmaxf(mt, __shfl_xor(mt, 32, 64));
  if (!__all(mt <= M + DT)) {
    const float Mn = fmaxf(M, mt);
    const float rs = exp2f((M - Mn) * SC);
    o0 *= rs; o1 *= rs; L *= rs; M = Mn; MS = M * SC;
  }
  float p[16];
  float lt = 0.f;
#pragma unroll
  for (int r = 0; r < 16; ++r) {
    p[r] = exp2f(__builtin_fmaf(sv[r], SC, -MS));
    lt += p[r];
  }
  lt += __shfl_xor(lt, 32, 64);
  L += lt;

  const unsigned c0 = pack2(p[0],  p[1]),  c1 = pack2(p[2],  p[3]);
  const unsigned c2 = pack2(p[4],  p[5]),  c3 = pack2(p[6],  p[7]);
  const unsigned c4 = pack2(p[8],  p[9]),  c5 = pack2(p[10], p[11]);
  const unsigned c6 = pack2(p[12], p[13]), c7 = pack2(p[14], p[15]);
  const unsigned x0 = __shfl_xor(c0, 32, 64), x1 = __shfl_xor(c1, 32, 64);
  const unsigned x2 = __shfl_xor(c2, 32, 64), x3 = __shfl_xor(c3, 32, 64);
  const unsigned x4 = __shfl_xor(c4, 32, 64), x5 = __shfl_xor(c5, 32, 64);
  const unsigned x6 = __shfl_xor(c6, 32, 64), x7 = __shfl_xor(c7, 32, 64);
  const bf16x8 pf0 = frag4(hi ? x2 : c0, hi ? x3 : c1, hi ? c2 : x0, hi ? c3 : x1);
  const bf16x8 pf1 = frag4(hi ? x6 : c4, hi ? x7 : c5, hi ? c6 : x4, hi ? c7 : x5);

  bf16x8 va;
  va = *(const bf16x8*)(vrow0 + kv0 + hi * 8);       o0 = MFMA32(va, pf0, o0);
  va = *(const bf16x8*)(vrow1 + kv0 + hi * 8);       o1 = MFMA32(va, pf0, o1);
  va = *(const bf16x8*)(vrow0 + kv0 + 16 + hi * 8);  o0 = MFMA32(va, pf1, o0);
  va = *(const bf16x8*)(vrow1 + kv0 + 16 + hi * 8);  o1 = MFMA32(va, pf1, o1);
}

__global__ __launch_bounds__(256, 4) void attn_kernel(
    const __bf16* __restrict__ Q, const __bf16* __restrict__ K,
    const __bf16* __restrict__ Vt, __bf16* __restrict__ Oc)
{
  const int bh  = blockIdx.x;
  const int p   = blockIdx.y;                   // pair: strips p and 63-p
  const int w   = threadIdx.x >> 6;
  const int lane = threadIdx.x & 63;
  const int l31 = lane & 31, hi = lane >> 5;
  const float SC = 0.18033688f;

  const __bf16* Qb = Q  + (size_t)bh * 131072;
  const __bf16* Kb = K  + (size_t)bh * 131072;
  const __bf16* Vb = Vt + (size_t)bh * 131072;
  const __bf16* vrow0 = Vb + (size_t)l31 * 2048;
  const __bf16* vrow1 = Vb + (size_t)(32 + l31) * 2048;

  __shared__ __bf16 SO[8][64][36];              // pad 36: stride 72B, 8B-aligned, ~2-way
  __shared__ float  SML[8][64][2];              // partial M, L

  const int qsS[2] = { p * 32, (63 - p) * 32 };
  const int nS[2]  = { p + 1, 64 - p };

#pragma unroll
  for (int ph = 0; ph < 2; ++ph) {
    const int qs = qsS[ph], nT = nS[ph];
    bf16x8 qf[4];
#pragma unroll
    for (int c = 0; c < 4; ++c)
      qf[c] = *(const bf16x8*)(Qb + (qs + l31) * 64 + c * 16 + hi * 8);

    f32x16v o0 = {}, o1 = {};
    float M = -1e30f, L = 0.f;
    float MS = M * SC;

    for (int t = w; t < nT; t += 4)
      attn_tile(Kb, vrow0, vrow1, qf, t * 32, t == nT - 1, l31, hi,
                M, MS, L, o0, o1);

    const int slot = ph * 4 + w;
#pragma unroll
    for (int q4 = 0; q4 < 4; ++q4) {
      bf16x4 a, b;
#pragma unroll
      for (int j = 0; j < 4; ++j) {
        a[j] = (__bf16)o0[q4 * 4 + j];
        b[j] = (__bf16)o1[q4 * 4 + j];
      }
      *(bf16x4*)&SO[slot][lane][q4 * 4]      = a;
      *(bf16x4*)&SO[slot][lane][16 + q4 * 4] = b;
    }
    SML[slot][lane][0] = M;
    SML[slot][lane][1] = L;
  }

  __syncthreads();
  if (w < 2) {                                  // wave 0 -> strip A, wave 1 -> strip B
    const int base = w * 4;
    const int qs = qsS[w];
    float Mw[4], Lw[4];
#pragma unroll
    for (int s = 0; s < 4; ++s) {
      Mw[s] = SML[base + s][lane][0];
      Lw[s] = SML[base + s][lane][1];
    }
    const float Ms = fmaxf(fmaxf(Mw[0], Mw[1]), fmaxf(Mw[2], Mw[3]));
    float r[4], Lt = 0.f;
#pragma unroll
    for (int s = 0; s < 4; ++s) {
      r[s] = exp2f((Mw[s] - Ms) * SC);
      Lt += Lw[s] * r[s];
    }
    const float inv = 1.0f / Lt;

    const int b = bh >> 4, h = bh & 15;
    const int tq = qs + l31;
    __bf16* orow = Oc + (size_t)(b * 2048 + tq) * 1024 + h * 64;
#pragma unroll
    for (int q4 = 0; q4 < 4; ++q4) {
      bf16x4 v0, v1;
      float acc0[4] = {}, acc1[4] = {};
#pragma unroll
      for (int s = 0; s < 4; ++s) {
        const bf16x4 a4 = *(const bf16x4*)&SO[base + s][lane][q4 * 4];
        const bf16x4 b4 = *(const bf16x4*)&SO[base + s][lane][16 + q4 * 4];
#pragma unroll
        for (int j = 0; j < 4; ++j) {
          acc0[j] += (float)a4[j] * r[s];
          acc1[j] += (float)b4[j] * r[s];
        }
      }
#pragma unroll
      for (int j = 0; j < 4; ++j) {
        v0[j] = (__bf16)(acc0[j] * inv);
        v1[j] = (__bf16)(acc1[j] * inv);
      }
      const int d0 = 8 * q4 + 4 * hi;
      *(bf16x4*)(orow + d0)      = v0;
      *(bf16x4*)(orow + 32 + d0) = v1;
    }
  }
}

extern "C" void kernel_launch(void* const* d_in, const int* in_sizes, int n_in,
                              void* d_out, int out_size, void* d_ws, size_t ws_size,
                              hipStream_t stream) {
  const float* x  = (const float*)d_in[0];
  const float* Wq = (const float*)d_in[1];
  const float* bq = (const float*)d_in[2];
  const float* Wk = (const float*)d_in[3];
  const float* bk = (const float*)d_in[4];
  const float* Wv = (const float*)d_in[5];
  const float* bv = (const float*)d_in[6];
  const float* Wp = (const float*)d_in[7];
  const float* bp = (const float*)d_in[8];

  __bf16* Qw  = (__bf16*)d_ws;                 // [32][2048][64]  8 MB
  __bf16* Kw  = Qw + (size_t)4194304;          // [32][2048][64]  8 MB
  __bf16* Vw  = Kw + (size_t)4194304;          // [32][64][2048]  8 MB (V^T)
  __bf16* xbA = Vw + (size_t)4194304;          // 8 MB: xb, then reused as Aw
  __bf16* Wb  = xbA + (size_t)4194304;         // [4][1024][1024] 8 MB bf16 weights

  conv_kernel<<<dim3(512, 5), 256, 0, stream>>>(x, Wq, Wk, Wv, Wp, xbA, Wb);
  gemm_qkv128<<<768, 256, 0, stream>>>(xbA, Wb, bq, bk, bv, Qw, Kw, Vw);
  attn_kernel<<<dim3(32, 32), 256, 0, stream>>>(Qw, Kw, Vw, xbA /*Aw*/);
  gemm_proj128<<<256, 256, 0, stream>>>(xbA /*Aw*/, Wb + (size_t)3 * 1048576,
                                        bp, (float*)d_out);
}

// Round 11
// 134.319 us; speedup vs baseline: 1.1221x; 1.0256x over previous
//
#include <hip/hip_runtime.h>
#include <hip/hip_bf16.h>
#include <stdint.h>

typedef __bf16 bf16x8 __attribute__((ext_vector_type(8)));
typedef __bf16 bf16x4 __attribute__((ext_vector_type(4)));
typedef __bf16 bf16x2 __attribute__((ext_vector_type(2)));
typedef float  f32x4  __attribute__((ext_vector_type(4)));
typedef float  f32x16v __attribute__((ext_vector_type(16)));

#define MFMA16(A,B,Cc) __builtin_amdgcn_mfma_f32_16x16x32_bf16(A,B,Cc,0,0,0)
#define MFMA32(A,B,Cc) __builtin_amdgcn_mfma_f32_32x32x16_bf16(A,B,Cc,0,0,0)

__device__ inline unsigned pack2(float a, float b) {
  union { bf16x2 v; unsigned u; } t;
  t.v[0] = (__bf16)a; t.v[1] = (__bf16)b;
  return t.u;
}
__device__ inline bf16x8 frag4(unsigned w0, unsigned w1, unsigned w2, unsigned w3) {
  union { unsigned u[4]; bf16x8 v; } t;
  t.u[0] = w0; t.u[1] = w1; t.u[2] = w2; t.u[3] = w3;
  return t.v;
}

// lane-half swap via permlane32_swap (pure VALU; no LDS latency).
// Validated on-hardware in round 9 (passed, absmax 0.0078).
__device__ inline void pswap(unsigned& a, unsigned& b) {
#if __has_builtin(__builtin_amdgcn_permlane32_swap)
  auto r = __builtin_amdgcn_permlane32_swap(a, b, false, false);
  a = r[0]; b = r[1];
#else
  asm volatile("v_permlane32_swap_b32 %0, %1" : "+v"(a), "+v"(b));
#endif
}
__device__ inline float cross32_max(float v) {
  unsigned a = __builtin_bit_cast(unsigned, v), b = a;
  pswap(a, b);
  return fmaxf(__builtin_bit_cast(float, a), __builtin_bit_cast(float, b));
}
__device__ inline float cross32_sum(float v) {
  unsigned a = __builtin_bit_cast(unsigned, v), b = a;
  pswap(a, b);
  return __builtin_bit_cast(float, a) + __builtin_bit_cast(float, b);
}

// async global->LDS, 16 B per lane; dest is wave-uniform base + lane*16
__device__ inline void gl16(const __bf16* g, __bf16* l) {
  __builtin_amdgcn_global_load_lds(
      (const __attribute__((address_space(1))) void*)(uintptr_t)g,
      (__attribute__((address_space(3))) void*)(uintptr_t)l, 16, 0, 0);
}

// ---------------- f32 -> bf16 pre-convert (x + 4 weight matrices) ----------------
__global__ __launch_bounds__(256) void conv_kernel(
    const float* __restrict__ x,
    const float* __restrict__ Wq, const float* __restrict__ Wk,
    const float* __restrict__ Wv, const float* __restrict__ Wp,
    __bf16* __restrict__ xb, __bf16* __restrict__ Wb)
{
  const int z = blockIdx.y;
  const float* src;
  __bf16* dst;
  int n4;
  if (z == 0) { src = x;  dst = xb; n4 = 1048576; }
  else {
    src = (z == 1) ? Wq : (z == 2) ? Wk : (z == 3) ? Wv : Wp;
    dst = Wb + (size_t)(z - 1) * 1048576;
    n4  = 262144;
  }
  const f32x4* s4 = (const f32x4*)src;
  for (int i = blockIdx.x * 256 + threadIdx.x; i < n4; i += gridDim.x * 256) {
    const f32x4 v = s4[i];
    bf16x4 o;
#pragma unroll
    for (int j = 0; j < 4; ++j) o[j] = (__bf16)v[j];
    *(bf16x4*)(dst + (size_t)i * 4) = o;
  }
}

// ---------------- shared 128x128x(K=1024) bf16 MFMA core (gload_lds staging) ----
__device__ inline void gemm_core(const __bf16* __restrict__ A,
                                 const __bf16* __restrict__ W,
                                 int m0, int n0,
                                 __bf16* As, __bf16* Bs,
                                 f32x4 (&acc)[4][4])
{
  const int tid = threadIdx.x, lane = tid & 63;
  const int wid = tid >> 6, wr = wid >> 1, wc = wid & 1;
  const int g = lane >> 4, cl = lane & 15;
  const int sr = tid >> 2, sk = (tid & 3) * 8;
  __bf16* AsW = As + (tid & 192) * 8;   // wave-uniform dest; lane*16B implied
  __bf16* BsW = Bs + (tid & 192) * 8;

  for (int k0 = 0; k0 < 1024; k0 += 32) {
    __syncthreads();                    // prev iter's LDS reads done
    gl16(A + (size_t)(m0 + sr)      * 1024 + k0 + sk, AsW);
    gl16(A + (size_t)(m0 + sr + 64) * 1024 + k0 + sk, AsW + 2048);
    gl16(W + (size_t)(n0 + sr)      * 1024 + k0 + sk, BsW);
    gl16(W + (size_t)(n0 + sr + 64) * 1024 + k0 + sk, BsW + 2048);
    __syncthreads();                    // vmcnt(0) drained before barrier
    bf16x8 af[4], bfr[4];
#pragma unroll
    for (int m = 0; m < 4; ++m)
      af[m] = *(const bf16x8*)(As + (wr * 64 + m * 16 + cl) * 32 + g * 8);
#pragma unroll
    for (int n = 0; n < 4; ++n)
      bfr[n] = *(const bf16x8*)(Bs + (wc * 64 + n * 16 + cl) * 32 + g * 8);
#pragma unroll
    for (int m = 0; m < 4; ++m)
#pragma unroll
      for (int n = 0; n < 4; ++n)
        acc[m][n] = MFMA16(af[m], bfr[n], acc[m][n]);
  }
}

// ---------------- fused QKV GEMM (bf16 in, scattered bf16 out) ----------------
__global__ __launch_bounds__(256) void gemm_qkv128(
    const __bf16* __restrict__ xb, const __bf16* __restrict__ Wb,
    const float* __restrict__ bq, const float* __restrict__ bk,
    const float* __restrict__ bv,
    __bf16* __restrict__ Qw, __bf16* __restrict__ Kw, __bf16* __restrict__ Vw)
{
  __shared__ __align__(16) __bf16 As[128 * 32];
  __shared__ __align__(16) __bf16 Bs[128 * 32];

  const int orig = blockIdx.x;
  const int wg   = (orig & 7) * 96 + (orig >> 3);   // bijective: 768 = 8*96
  const int z    = wg >> 8;
  const int rem  = wg & 255;
  const int m0   = (rem >> 3) * 128;
  const int n0   = (rem & 7) * 128;

  const __bf16* W  = Wb + (size_t)z * 1048576;
  const float*  bi = (z == 0) ? bq : (z == 1) ? bk : bv;
  __bf16*       out = (z == 0) ? Qw : (z == 1) ? Kw : Vw;

  f32x4 acc[4][4] = {};
  gemm_core(xb, W, m0, n0, As, Bs, acc);

  const int lane = threadIdx.x & 63, wid = threadIdx.x >> 6;
  const int wr = wid >> 1, wc = wid & 1;
  const int g = lane >> 4, cl = lane & 15;

  float bvv[4];
#pragma unroll
  for (int n = 0; n < 4; ++n) bvv[n] = bi[n0 + wc * 64 + n * 16 + cl];

#pragma unroll
  for (int m = 0; m < 4; ++m)
#pragma unroll
    for (int n = 0; n < 4; ++n) {
      const int col = n0 + wc * 64 + n * 16 + cl;
      const int h = col >> 6, d = col & 63;
      if (z == 2) {                               // V^T scatter [BH][D][T]
        const int row0 = m0 + wr * 64 + m * 16 + g * 4;
        const int b2 = row0 >> 11, t0 = row0 & 2047;
        bf16x4 v4;
#pragma unroll
        for (int j = 0; j < 4; ++j) v4[j] = (__bf16)(acc[m][n][j] + bvv[n]);
        *(bf16x4*)(out + (size_t)(b2 * 16 + h) * 131072 + (size_t)d * 2048 + t0) = v4;
      } else {                                    // Q/K scatter [BH][T][D]
#pragma unroll
        for (int j = 0; j < 4; ++j) {
          const int row = m0 + wr * 64 + m * 16 + g * 4 + j;
          const int b2 = row >> 11, t = row & 2047;
          out[(size_t)(b2 * 16 + h) * 131072 + (size_t)t * 64 + d] =
              (__bf16)(acc[m][n][j] + bvv[n]);
        }
      }
    }
}

// ---------------- projection GEMM (bf16 in, f32 out) ----------------
__global__ __launch_bounds__(256) void gemm_proj128(
    const __bf16* __restrict__ A, const __bf16* __restrict__ W,
    const float* __restrict__ bi, float* __restrict__ outp)
{
  __shared__ __align__(16) __bf16 As[128 * 32];
  __shared__ __align__(16) __bf16 Bs[128 * 32];

  const int orig = blockIdx.x;
  const int wg   = (orig & 7) * 32 + (orig >> 3);   // bijective: 256 = 8*32
  const int m0   = (wg >> 3) * 128;
  const int n0   = (wg & 7) * 128;

  f32x4 acc[4][4] = {};
  gemm_core(A, W, m0, n0, As, Bs, acc);

  const int lane = threadIdx.x & 63, wid = threadIdx.x >> 6;
  const int wr = wid >> 1, wc = wid & 1;
  const int g = lane >> 4, cl = lane & 15;

  float bvv[4];
#pragma unroll
  for (int n = 0; n < 4; ++n) bvv[n] = bi[n0 + wc * 64 + n * 16 + cl];
#pragma unroll
  for (int m = 0; m < 4; ++m)
#pragma unroll
    for (int n = 0; n < 4; ++n) {
      const int col = n0 + wc * 64 + n * 16 + cl;
#pragma unroll
      for (int j = 0; j < 4; ++j) {
        const int row = m0 + wr * 64 + m * 16 + g * 4 + j;
        outp[(size_t)row * 1024 + col] = acc[m][n][j] + bvv[n];
      }
    }
}

// ---------------- causal flash attention: strip-paired + permlane softmax ----------
// r10 structure; only change: all cross-lane ops are permlane32_swap (VALU),
// V loads hoisted to tile start (same addresses -> same L2 pattern).
__device__ inline void attn_tile(
    const __bf16* __restrict__ Kb, const __bf16* __restrict__ vrow0,
    const __bf16* __restrict__ vrow1, const bf16x8 (&qf)[4],
    int kv0, bool diag, int l31, int hi,
    float& M, float& MS, float& L, f32x16v& o0, f32x16v& o1)
{
  const float SC = 0.18033688f;                 // 0.125 * log2(e)
  const float DT = 16.6f;                       // defer-max: P bounded by 2^3

  // issue all 8 loads of this tile together: V latency hides under QK+softmax
  const bf16x8 kf0 = *(const bf16x8*)(Kb + (kv0 + l31) * 64 +      hi * 8);
  const bf16x8 kf1 = *(const bf16x8*)(Kb + (kv0 + l31) * 64 + 16 + hi * 8);
  const bf16x8 kf2 = *(const bf16x8*)(Kb + (kv0 + l31) * 64 + 32 + hi * 8);
  const bf16x8 kf3 = *(const bf16x8*)(Kb + (kv0 + l31) * 64 + 48 + hi * 8);
  const bf16x8 va0 = *(const bf16x8*)(vrow0 + kv0 + hi * 8);
  const bf16x8 va1 = *(const bf16x8*)(vrow1 + kv0 + hi * 8);
  const bf16x8 va2 = *(const bf16x8*)(vrow0 + kv0 + 16 + hi * 8);
  const bf16x8 va3 = *(const bf16x8*)(vrow1 + kv0 + 16 + hi * 8);

  f32x16v s = {};
  s = MFMA32(kf0, qf[0], s);
  s = MFMA32(kf1, qf[1], s);
  s = MFMA32(kf2, qf[2], s);
  s = MFMA32(kf3, qf[3], s);

  if (diag) {                                   // mask k > q in place
#pragma unroll
    for (int r = 0; r < 16; ++r) {
      const int kl = (r & 3) + 8 * (r >> 2) + 4 * hi;
      if (kl > l31) s[r] = -1e30f;
    }
  }
  float mt = fmaxf(s[0], s[1]);
#pragma unroll
  for (int r = 2; r < 16; ++r) mt = fmaxf(mt, s[r]);
  mt = cross32_max(mt);
  if (!__all(mt <= M + DT)) {
    const float Mn = fmaxf(M, mt);
    const float rs = exp2f((M - Mn) * SC);
    o0 *= rs; o1 *= rs; L *= rs; M = Mn; MS = M * SC;
  }
  float pr[16];
  float lt = 0.f;
#pragma unroll
  for (int r = 0; r < 16; ++r) {
    pr[r] = exp2f(__builtin_fmaf(s[r], SC, -MS));
    lt += pr[r];
  }
  L += cross32_sum(lt);

  // P-pack: 8 cvt-pack + 4 permlane32_swap (no LDS cross-lane ops, no selects)
  unsigned c0 = pack2(pr[0],  pr[1]),  c1 = pack2(pr[2],  pr[3]);
  unsigned c2 = pack2(pr[4],  pr[5]),  c3 = pack2(pr[6],  pr[7]);
  unsigned c4 = pack2(pr[8],  pr[9]),  c5 = pack2(pr[10], pr[11]);
  unsigned c6 = pack2(pr[12], pr[13]), c7 = pack2(pr[14], pr[15]);
  pswap(c0, c2);
  pswap(c1, c3);
  pswap(c4, c6);
  pswap(c5, c7);
  const bf16x8 pf0 = frag4(c0, c1, c2, c3);
  const bf16x8 pf1 = frag4(c4, c5, c6, c7);

  o0 = MFMA32(va0, pf0, o0);
  o1 = MFMA32(va1, pf0, o1);
  o0 = MFMA32(va2, pf1, o0);
  o1 = MFMA32(va3, pf1, o1);
}

__global__ __launch_bounds__(256, 4) void attn_kernel(
    const __bf16* __restrict__ Q, const __bf16* __restrict__ K,
    const __bf16* __restrict__ Vt, __bf16* __restrict__ Oc)
{
  const int bh  = blockIdx.x;
  const int p   = blockIdx.y;                   // pair: strips p and 63-p
  const int w   = threadIdx.x >> 6;
  const int lane = threadIdx.x & 63;
  const int l31 = lane & 31, hi = lane >> 5;
  const float SC = 0.18033688f;

  const __bf16* Qb = Q  + (size_t)bh * 131072;
  const __bf16* Kb = K  + (size_t)bh * 131072;
  const __bf16* Vb = Vt + (size_t)bh * 131072;
  const __bf16* vrow0 = Vb + (size_t)l31 * 2048;
  const __bf16* vrow1 = Vb + (size_t)(32 + l31) * 2048;

  __shared__ __bf16 SO[8][64][36];              // pad 36: stride 72B, 8B-aligned
  __shared__ float  SML[8][64][2];              // partial M, L

  const int qsS[2] = { p * 32, (63 - p) * 32 };
  const int nS[2]  = { p + 1, 64 - p };

#pragma unroll
  for (int ph = 0; ph < 2; ++ph) {
    const int qs = qsS[ph], nT = nS[ph];
    bf16x8 qf[4];
#pragma unroll
    for (int c = 0; c < 4; ++c)
      qf[c] = *(const bf16x8*)(Qb + (qs + l31) * 64 + c * 16 + hi * 8);

    f32x16v o0 = {}, o1 = {};
    float M = -1e30f, L = 0.f;
    float MS = M * SC;

    for (int t = w; t < nT; t += 4)
      attn_tile(Kb, vrow0, vrow1, qf, t * 32, t == nT - 1, l31, hi,
                M, MS, L, o0, o1);

    const int slot = ph * 4 + w;
#pragma unroll
    for (int q4 = 0; q4 < 4; ++q4) {
      bf16x4 a, b;
#pragma unroll
      for (int j = 0; j < 4; ++j) {
        a[j] = (__bf16)o0[q4 * 4 + j];
        b[j] = (__bf16)o1[q4 * 4 + j];
      }
      *(bf16x4*)&SO[slot][lane][q4 * 4]      = a;
      *(bf16x4*)&SO[slot][lane][16 + q4 * 4] = b;
    }
    SML[slot][lane][0] = M;
    SML[slot][lane][1] = L;
  }

  __syncthreads();
  if (w < 2) {                                  // wave 0 -> strip A, wave 1 -> strip B
    const int base = w * 4;
    const int qs = qsS[w];
    float Mw[4], Lw[4];
#pragma unroll
    for (int s = 0; s < 4; ++s) {
      Mw[s] = SML[base + s][lane][0];
      Lw[s] = SML[base + s][lane][1];
    }
    const float Ms = fmaxf(fmaxf(Mw[0], Mw[1]), fmaxf(Mw[2], Mw[3]));
    float r[4], Lt = 0.f;
#pragma unroll
    for (int s = 0; s < 4; ++s) {
      r[s] = exp2f((Mw[s] - Ms) * SC);
      Lt += Lw[s] * r[s];
    }
    const float inv = 1.0f / Lt;

    const int b = bh >> 4, h = bh & 15;
    const int tq = qs + l31;
    __bf16* orow = Oc + (size_t)(b * 2048 + tq) * 1024 + h * 64;
#pragma unroll
    for (int q4 = 0; q4 < 4; ++q4) {
      bf16x4 v0, v1;
      float acc0[4] = {}, acc1[4] = {};
#pragma unroll
      for (int s = 0; s < 4; ++s) {
        const bf16x4 a4 = *(const bf16x4*)&SO[base + s][lane][q4 * 4];
        const bf16x4 b4 = *(const bf16x4*)&SO[base + s][lane][16 + q4 * 4];
#pragma unroll
        for (int j = 0; j < 4; ++j) {
          acc0[j] += (float)a4[j] * r[s];
          acc1[j] += (float)b4[j] * r[s];
        }
      }
#pragma unroll
      for (int j = 0; j < 4; ++j) {
        v0[j] = (__bf16)(acc0[j] * inv);
        v1[j] = (__bf16)(acc1[j] * inv);
      }
      const int d0 = 8 * q4 + 4 * hi;
      *(bf16x4*)(orow + d0)      = v0;
      *(bf16x4*)(orow + 32 + d0) = v1;
    }
  }
}

extern "C" void kernel_launch(void* const* d_in, const int* in_sizes, int n_in,
                              void* d_out, int out_size, void* d_ws, size_t ws_size,
                              hipStream_t stream) {
  const float* x  = (const float*)d_in[0];
  const float* Wq = (const float*)d_in[1];
  const float* bq = (const float*)d_in[2];
  const float* Wk = (const float*)d_in[3];
  const float* bk = (const float*)d_in[4];
  const float* Wv = (const float*)d_in[5];
  const float* bv = (const float*)d_in[6];
  const float* Wp = (const float*)d_in[7];
  const float* bp = (const float*)d_in[8];

  __bf16* Qw  = (__bf16*)d_ws;                 // [32][2048][64]  8 MB
  __bf16* Kw  = Qw + (size_t)4194304;          // [32][2048][64]  8 MB
  __bf16* Vw  = Kw + (size_t)4194304;          // [32][64][2048]  8 MB (V^T)
  __bf16* xbA = Vw + (size_t)4194304;          // 8 MB: xb, then reused as Aw
  __bf16* Wb  = xbA + (size_t)4194304;         // [4][1024][1024] 8 MB bf16 weights

  conv_kernel<<<dim3(512, 5), 256, 0, stream>>>(x, Wq, Wk, Wv, Wp, xbA, Wb);
  gemm_qkv128<<<768, 256, 0, stream>>>(xbA, Wb, bq, bk, bv, Qw, Kw, Vw);
  attn_kernel<<<dim3(32, 32), 256, 0, stream>>>(Qw, Kw, Vw, xbA /*Aw*/);
  gemm_proj128<<<256, 256, 0, stream>>>(xbA /*Aw*/, Wb + (size_t)3 * 1048576,
                                        bp, (float*)d_out);
}